// Round 18
// baseline (152.209 us; speedup 1.0000x reference)
//
#include <hip/hip_runtime.h>
#include <hip/hip_bf16.h>
#include <stdint.h>

#define D_MODEL 1024

typedef __attribute__((ext_vector_type(4))) float  f32x4;
typedef __attribute__((ext_vector_type(8))) __bf16 bf16x8;
typedef __attribute__((ext_vector_type(8))) unsigned short u16x8;
typedef __attribute__((ext_vector_type(4))) unsigned short u16x4;

// ---------- helpers ----------

__device__ __forceinline__ unsigned short f2bf(float f) {
    unsigned u = __float_as_uint(f);
    u += 0x7fffu + ((u >> 16) & 1u);
    return (unsigned short)(u >> 16);
}

// ---------- prelude (3 launches, atomic-free; R17 colmax — proven) ----------

// blocks [0,2048): x colmax + bf16 convert, 16 rows/block, 8 cols/thread,
//   16B nontemporal Xb stores (Xb can't L2-fit; NT avoids polluting L2).
// blocks [2048,2064): w colmax partials (64 rows each).
#define CC_ROWS 16
__global__ __launch_bounds__(256)
void colmax_convert_w(const float* __restrict__ x, const float* __restrict__ w,
                      float* __restrict__ partial, float* __restrict__ partial3,
                      unsigned short* __restrict__ xb) {
    if (blockIdx.x < 2048) {
        __shared__ float cmb[128 * 8];
        int rr = threadIdx.x >> 7;            // 0..1 row-half
        int c8 = (threadIdx.x & 127) * 8;     // 8 cols/thread
        size_t row0 = (size_t)blockIdx.x * CC_ROWS;
        f32x4 m0 = {-__builtin_inff(), -__builtin_inff(), -__builtin_inff(), -__builtin_inff()};
        f32x4 m1 = m0;
#pragma unroll
        for (int r = rr; r < CC_ROWS; r += 2) {
            const float* p = &x[(row0 + r) * D_MODEL + c8];
            f32x4 v0 = *reinterpret_cast<const f32x4*>(p);
            f32x4 v1 = *reinterpret_cast<const f32x4*>(p + 4);
            u16x8 o;
#pragma unroll
            for (int e = 0; e < 4; ++e) {
                m0[e] = fmaxf(m0[e], v0[e]);  o[e]     = f2bf(v0[e]);
                m1[e] = fmaxf(m1[e], v1[e]);  o[e + 4] = f2bf(v1[e]);
            }
            __builtin_nontemporal_store(
                o, reinterpret_cast<u16x8*>(&xb[(row0 + r) * D_MODEL + c8]));
        }
        if (rr == 1) {
            *reinterpret_cast<f32x4*>(&cmb[(threadIdx.x & 127) * 8])     = m0;
            *reinterpret_cast<f32x4*>(&cmb[(threadIdx.x & 127) * 8 + 4]) = m1;
        }
        __syncthreads();
        if (rr == 0) {
            f32x4 o0 = *reinterpret_cast<const f32x4*>(&cmb[(threadIdx.x & 127) * 8]);
            f32x4 o1 = *reinterpret_cast<const f32x4*>(&cmb[(threadIdx.x & 127) * 8 + 4]);
#pragma unroll
            for (int e = 0; e < 4; ++e) { m0[e] = fmaxf(m0[e], o0[e]); m1[e] = fmaxf(m1[e], o1[e]); }
            *reinterpret_cast<f32x4*>(&partial[(size_t)blockIdx.x * D_MODEL + c8])     = m0;
            *reinterpret_cast<f32x4*>(&partial[(size_t)blockIdx.x * D_MODEL + c8 + 4]) = m1;
        }
    } else {
        int c4 = threadIdx.x * 4;
        int wb = blockIdx.x - 2048;                  // 0..15
        size_t base = (size_t)wb * 64 * D_MODEL + c4;
        f32x4 m4 = {-__builtin_inff(), -__builtin_inff(), -__builtin_inff(), -__builtin_inff()};
#pragma unroll 8
        for (int r = 0; r < 64; ++r) {
            f32x4 v = *reinterpret_cast<const f32x4*>(&w[base + (size_t)r * D_MODEL]);
#pragma unroll
            for (int e = 0; e < 4; ++e) m4[e] = fmaxf(m4[e], v[e]);
        }
        *reinterpret_cast<f32x4*>(&partial3[(size_t)wb * D_MODEL + c4]) = m4;
    }
}

__global__ void reduce_partial(const float* __restrict__ partial,
                               float* __restrict__ partial2) {
    int col = blockIdx.x * 256 + threadIdx.x;
    int b0  = blockIdx.y * 64;
    float m = -__builtin_inff();
#pragma unroll 8
    for (int i = 0; i < 64; ++i)
        m = fmaxf(m, partial[(size_t)(b0 + i) * D_MODEL + col]);
    partial2[(size_t)blockIdx.y * D_MODEL + col] = m;
}

__global__ __launch_bounds__(256)
void scale_buildw(const float* __restrict__ partial2, const float* __restrict__ partial3,
                  const float* __restrict__ W, unsigned short* __restrict__ Wp) {
    __shared__ float s_lds[D_MODEL];
    int k4 = threadIdx.x * 4;
    f32x4 ma = {-__builtin_inff(), -__builtin_inff(), -__builtin_inff(), -__builtin_inff()};
#pragma unroll 8
    for (int i = 0; i < 32; ++i) {
        f32x4 v = *reinterpret_cast<const f32x4*>(&partial2[(size_t)i * D_MODEL + k4]);
#pragma unroll
        for (int e = 0; e < 4; ++e) ma[e] = fmaxf(ma[e], v[e]);
    }
    f32x4 mw = {-__builtin_inff(), -__builtin_inff(), -__builtin_inff(), -__builtin_inff()};
#pragma unroll 8
    for (int i = 0; i < 16; ++i) {
        f32x4 v = *reinterpret_cast<const f32x4*>(&partial3[(size_t)i * D_MODEL + k4]);
#pragma unroll
        for (int e = 0; e < 4; ++e) mw[e] = fmaxf(mw[e], v[e]);
    }
    f32x4 sk;
#pragma unroll
    for (int e = 0; e < 4; ++e) sk[e] = sqrtf(ma[e]) / sqrtf(mw[e]);
    *reinterpret_cast<f32x4*>(&s_lds[k4]) = sk;
    __syncthreads();

    int j  = blockIdx.x;
    float sj = s_lds[j];
    f32x4 wv = *reinterpret_cast<const f32x4*>(&W[(size_t)j * D_MODEL + k4]);
    u16x4 o;
#pragma unroll
    for (int i = 0; i < 4; ++i) o[i] = f2bf(sj * wv[i] / sk[i]);
    *reinterpret_cast<u16x4*>(&Wp[(size_t)j * D_MODEL + k4]) = o;
}

// ---------- GEMM: R16 verbatim (normal C-stores — NT regressed, reverted) ----
// 128x256 tile, 4 waves (2Mx2N), BK=32, triple buffer, counted vmcnt(6).
// 72 KB LDS, 2 blocks/CU. 8-variant-robust plateau ~88 µs @ 33% MfmaUtil.
#define GBM 128
#define GBN 256
#define GBK 32
#define GNT (D_MODEL / GBK)    // 32
#define ABUF_SHORTS 4096       // A: 8 KB per buffer
#define BBUF_SHORTS 8192       // B: 16 KB per buffer

__global__ __launch_bounds__(256, 2)
void gemm_main(const unsigned short* __restrict__ Xb,
               const unsigned short* __restrict__ Wp,
               const float* __restrict__ bias,
               float* __restrict__ out) {
    __shared__ __align__(16) unsigned short lds[3 * ABUF_SHORTS + 3 * BBUF_SHORTS];

    int flat  = blockIdx.x;
    int xcd   = flat & 7;
    int j     = flat >> 3;                      // 0..127
    int col0  = (j & 3) * GBN;                  // 4 col panels
    int row0  = ((xcd << 5) + (j >> 2)) * GBM;  // chunk 0..255, within-XCD reuse

    int tid  = threadIdx.x;
    int wave = tid >> 6;
    int lane = tid & 63;
    int wr   = wave >> 1;      // 0..1 : rows wr*64
    int wc   = wave & 1;       // 0..1 : cols wc*128
    int l16  = lane & 15;
    int lq   = lane >> 4;      // 0..3 : k-quarter (8 bf16)

    int sline = lane >> 3;
    int slog  = (lane & 7) ^ sline;
    int sh    = slog >> 2;
    int sq    = slog & 3;

    f32x4 acc[4][8];
#pragma unroll
    for (int m = 0; m < 4; ++m)
#pragma unroll
        for (int n = 0; n < 8; ++n)
            acc[m][n] = (f32x4){0.f, 0.f, 0.f, 0.f};

    auto stage = [&](int t, int b) {
        int k0 = t * GBK;
#pragma unroll
        for (int r = 0; r < 2; ++r) {
            int line = r * 32 + wave * 8 + sline;     // 0..63
            const unsigned short* gA =
                Xb + (size_t)(row0 + 2 * line + sh) * D_MODEL + k0 + sq * 8;
            __builtin_amdgcn_global_load_lds(
                (const __attribute__((address_space(1))) void*)gA,
                (__attribute__((address_space(3))) void*)&lds[b * ABUF_SHORTS + line * 64],
                16, 0, 0);
        }
#pragma unroll
        for (int r = 0; r < 4; ++r) {
            int line = r * 32 + wave * 8 + sline;     // 0..127
            const unsigned short* gB =
                Wp + (size_t)(col0 + 2 * line + sh) * D_MODEL + k0 + sq * 8;
            __builtin_amdgcn_global_load_lds(
                (const __attribute__((address_space(1))) void*)gB,
                (__attribute__((address_space(3))) void*)&lds[3 * ABUF_SHORTS + b * BBUF_SHORTS + line * 64],
                16, 0, 0);
        }
    };

    stage(0, 0);
    stage(1, 1);

    int cur = 0;   // t % 3
#pragma unroll 1
    for (int t = 0; t < GNT; ++t) {
        if (t + 1 < GNT) asm volatile("s_waitcnt vmcnt(6)" ::: "memory");
        else             asm volatile("s_waitcnt vmcnt(0)" ::: "memory");
        __builtin_amdgcn_s_barrier();

        if (t + 2 < GNT) {
            int bnext = cur >= 1 ? cur - 1 : cur + 2;   // (t+2)%3
            stage(t + 2, bnext);
        }

        const char* Ab = (const char*)&lds[cur * ABUF_SHORTS];
        const char* Bb = (const char*)&lds[3 * ABUF_SHORTS + cur * BBUF_SHORTS];

        bf16x8 bfr[8];
#pragma unroll
        for (int n = 0; n < 8; ++n) {
            int cc   = wc * 128 + n * 16 + l16;
            int line = cc >> 1;
            int o    = (((cc & 1) << 6) + (lq << 4)) ^ ((line & 7) << 4);
            bfr[n] = *reinterpret_cast<const bf16x8*>(Bb + line * 128 + o);
        }
        bf16x8 afr[4];
#pragma unroll
        for (int m = 0; m < 4; ++m) {
            int rr   = wr * 64 + m * 16 + l16;
            int line = rr >> 1;
            int o    = (((rr & 1) << 6) + (lq << 4)) ^ ((line & 7) << 4);
            afr[m] = *reinterpret_cast<const bf16x8*>(Ab + line * 128 + o);
        }

        __builtin_amdgcn_s_setprio(1);
#pragma unroll
        for (int m = 0; m < 4; ++m)
#pragma unroll
            for (int n = 0; n < 8; ++n)
                acc[m][n] = __builtin_amdgcn_mfma_f32_16x16x32_bf16(
                    afr[m], bfr[n], acc[m][n], 0, 0, 0);
        __builtin_amdgcn_s_setprio(0);

        cur = cur == 2 ? 0 : cur + 1;
    }

    // ---- epilogue: C/D col = lane&15, row = lq*4 + q; NORMAL stores ----
    // (NT C-stores regressed: 64B/wave chunks need L2 write-combining;
    //  NT bypassed it -> WRITE_SIZE 144->163 MB, +11 µs. Reverted.)
    int crow = row0 + wr * 64;
    int ccol = col0 + wc * 128;
#pragma unroll
    for (int n = 0; n < 8; ++n) {
        int col = ccol + n * 16 + l16;
        float b = bias[col];
#pragma unroll
        for (int m = 0; m < 4; ++m) {
            int r = crow + m * 16 + lq * 4;
#pragma unroll
            for (int q = 0; q < 4; ++q)
                out[(size_t)(r + q) * D_MODEL + col] = acc[m][n][q] + b;
        }
    }
}

// ---------- launch ----------

extern "C" void kernel_launch(void* const* d_in, const int* in_sizes, int n_in,
                              void* d_out, int out_size, void* d_ws, size_t ws_size,
                              hipStream_t stream) {
    const float* x    = (const float*)d_in[0];
    const float* w    = (const float*)d_in[1];
    const float* bias = (const float*)d_in[2];
    float* out        = (float*)d_out;
    const int N       = in_sizes[0] / D_MODEL;   // 32768

    // ws: [16K, +2M) Wp | Xb (64M) | partial (8M) | partial2 (128K) | partial3 (64K)
    char* ws               = (char*)d_ws;
    unsigned short* Wp     = (unsigned short*)(ws + 16384);
    unsigned short* Xb     = (unsigned short*)(ws + 16384 + (size_t)D_MODEL * D_MODEL * 2);
    const int nPart        = N / CC_ROWS;   // 2048
    char*  after_xb        = ws + 16384 + (size_t)D_MODEL * D_MODEL * 2
                                        + (size_t)N * D_MODEL * 2;
    float* part            = (float*)after_xb;                                   // 2048 x 1024
    float* part2           = (float*)(after_xb + (size_t)nPart * D_MODEL * 4);   // 32 x 1024
    float* part3           = (float*)(after_xb + (size_t)nPart * D_MODEL * 4
                                               + (size_t)32 * D_MODEL * 4);      // 16 x 1024

    colmax_convert_w<<<nPart + 16, 256, 0, stream>>>(x, w, part, part3, Xb);
    reduce_partial<<<dim3(D_MODEL / 256, 32), 256, 0, stream>>>(part, part2);
    scale_buildw<<<D_MODEL, 256, 0, stream>>>(part2, part3, w, Wp);

    int nblk = (N / GBM) * (D_MODEL / GBN);   // 1024
    gemm_main<<<nblk, 256, 0, stream>>>(Xb, Wp, bias, out);
}

// Round 19
// 145.590 us; speedup vs baseline: 1.0455x; 1.0455x over previous
//
#include <hip/hip_runtime.h>
#include <hip/hip_bf16.h>
#include <stdint.h>

#define D_MODEL 1024

typedef __attribute__((ext_vector_type(4))) float  f32x4;
typedef __attribute__((ext_vector_type(8))) __bf16 bf16x8;
typedef __attribute__((ext_vector_type(8))) unsigned short u16x8;
typedef __attribute__((ext_vector_type(4))) unsigned short u16x4;

// ---------- helpers ----------

__device__ __forceinline__ unsigned short f2bf(float f) {
    unsigned u = __float_as_uint(f);
    u += 0x7fffu + ((u >> 16) & 1u);
    return (unsigned short)(u >> 16);
}

// ---------- prelude (3 launches, atomic-free) ----------

// blocks [0,2048): x colmax + bf16 convert, 16 rows/block, 8 cols/thread,
//   16B NORMAL Xb stores. (NT Xb stores regressed the GEMM by 8 µs: they
//   bypass L2/L3 on write, so Xb was cache-cold for the GEMM's A-fetch —
//   FETCH 52->61 MB. L2/L3-warm Xb is load-bearing. R18 lesson.)
// blocks [2048,2064): w colmax partials (64 rows each).
#define CC_ROWS 16
__global__ __launch_bounds__(256)
void colmax_convert_w(const float* __restrict__ x, const float* __restrict__ w,
                      float* __restrict__ partial, float* __restrict__ partial3,
                      unsigned short* __restrict__ xb) {
    if (blockIdx.x < 2048) {
        __shared__ float cmb[128 * 8];
        int rr = threadIdx.x >> 7;            // 0..1 row-half
        int c8 = (threadIdx.x & 127) * 8;     // 8 cols/thread
        size_t row0 = (size_t)blockIdx.x * CC_ROWS;
        f32x4 m0 = {-__builtin_inff(), -__builtin_inff(), -__builtin_inff(), -__builtin_inff()};
        f32x4 m1 = m0;
#pragma unroll
        for (int r = rr; r < CC_ROWS; r += 2) {
            const float* p = &x[(row0 + r) * D_MODEL + c8];
            f32x4 v0 = *reinterpret_cast<const f32x4*>(p);
            f32x4 v1 = *reinterpret_cast<const f32x4*>(p + 4);
            u16x8 o;
#pragma unroll
            for (int e = 0; e < 4; ++e) {
                m0[e] = fmaxf(m0[e], v0[e]);  o[e]     = f2bf(v0[e]);
                m1[e] = fmaxf(m1[e], v1[e]);  o[e + 4] = f2bf(v1[e]);
            }
            *reinterpret_cast<u16x8*>(&xb[(row0 + r) * D_MODEL + c8]) = o;
        }
        if (rr == 1) {
            *reinterpret_cast<f32x4*>(&cmb[(threadIdx.x & 127) * 8])     = m0;
            *reinterpret_cast<f32x4*>(&cmb[(threadIdx.x & 127) * 8 + 4]) = m1;
        }
        __syncthreads();
        if (rr == 0) {
            f32x4 o0 = *reinterpret_cast<const f32x4*>(&cmb[(threadIdx.x & 127) * 8]);
            f32x4 o1 = *reinterpret_cast<const f32x4*>(&cmb[(threadIdx.x & 127) * 8 + 4]);
#pragma unroll
            for (int e = 0; e < 4; ++e) { m0[e] = fmaxf(m0[e], o0[e]); m1[e] = fmaxf(m1[e], o1[e]); }
            *reinterpret_cast<f32x4*>(&partial[(size_t)blockIdx.x * D_MODEL + c8])     = m0;
            *reinterpret_cast<f32x4*>(&partial[(size_t)blockIdx.x * D_MODEL + c8 + 4]) = m1;
        }
    } else {
        int c4 = threadIdx.x * 4;
        int wb = blockIdx.x - 2048;                  // 0..15
        size_t base = (size_t)wb * 64 * D_MODEL + c4;
        f32x4 m4 = {-__builtin_inff(), -__builtin_inff(), -__builtin_inff(), -__builtin_inff()};
#pragma unroll 8
        for (int r = 0; r < 64; ++r) {
            f32x4 v = *reinterpret_cast<const f32x4*>(&w[base + (size_t)r * D_MODEL]);
#pragma unroll
            for (int e = 0; e < 4; ++e) m4[e] = fmaxf(m4[e], v[e]);
        }
        *reinterpret_cast<f32x4*>(&partial3[(size_t)wb * D_MODEL + c4]) = m4;
    }
}

__global__ void reduce_partial(const float* __restrict__ partial,
                               float* __restrict__ partial2) {
    int col = blockIdx.x * 256 + threadIdx.x;
    int b0  = blockIdx.y * 64;
    float m = -__builtin_inff();
#pragma unroll 8
    for (int i = 0; i < 64; ++i)
        m = fmaxf(m, partial[(size_t)(b0 + i) * D_MODEL + col]);
    partial2[(size_t)blockIdx.y * D_MODEL + col] = m;
}

__global__ __launch_bounds__(256)
void scale_buildw(const float* __restrict__ partial2, const float* __restrict__ partial3,
                  const float* __restrict__ W, unsigned short* __restrict__ Wp) {
    __shared__ float s_lds[D_MODEL];
    int k4 = threadIdx.x * 4;
    f32x4 ma = {-__builtin_inff(), -__builtin_inff(), -__builtin_inff(), -__builtin_inff()};
#pragma unroll 8
    for (int i = 0; i < 32; ++i) {
        f32x4 v = *reinterpret_cast<const f32x4*>(&partial2[(size_t)i * D_MODEL + k4]);
#pragma unroll
        for (int e = 0; e < 4; ++e) ma[e] = fmaxf(ma[e], v[e]);
    }
    f32x4 mw = {-__builtin_inff(), -__builtin_inff(), -__builtin_inff(), -__builtin_inff()};
#pragma unroll 8
    for (int i = 0; i < 16; ++i) {
        f32x4 v = *reinterpret_cast<const f32x4*>(&partial3[(size_t)i * D_MODEL + k4]);
#pragma unroll
        for (int e = 0; e < 4; ++e) mw[e] = fmaxf(mw[e], v[e]);
    }
    f32x4 sk;
#pragma unroll
    for (int e = 0; e < 4; ++e) sk[e] = sqrtf(ma[e]) / sqrtf(mw[e]);
    *reinterpret_cast<f32x4*>(&s_lds[k4]) = sk;
    __syncthreads();

    int j  = blockIdx.x;
    float sj = s_lds[j];
    f32x4 wv = *reinterpret_cast<const f32x4*>(&W[(size_t)j * D_MODEL + k4]);
    u16x4 o;
#pragma unroll
    for (int i = 0; i < 4; ++i) o[i] = f2bf(sj * wv[i] / sk[i]);
    *reinterpret_cast<u16x4*>(&Wp[(size_t)j * D_MODEL + k4]) = o;
}

// ---------- GEMM: R16 verbatim (best measured structure: ~88 µs) ----------
// 128x256 tile, 4 waves (2Mx2N), BK=32, triple buffer, counted vmcnt(6).
// 72 KB LDS, 2 blocks/CU. Normal C-stores (L2 write-combining needed).
#define GBM 128
#define GBN 256
#define GBK 32
#define GNT (D_MODEL / GBK)    // 32
#define ABUF_SHORTS 4096       // A: 8 KB per buffer
#define BBUF_SHORTS 8192       // B: 16 KB per buffer

__global__ __launch_bounds__(256, 2)
void gemm_main(const unsigned short* __restrict__ Xb,
               const unsigned short* __restrict__ Wp,
               const float* __restrict__ bias,
               float* __restrict__ out) {
    __shared__ __align__(16) unsigned short lds[3 * ABUF_SHORTS + 3 * BBUF_SHORTS];

    int flat  = blockIdx.x;
    int xcd   = flat & 7;
    int j     = flat >> 3;                      // 0..127
    int col0  = (j & 3) * GBN;                  // 4 col panels
    int row0  = ((xcd << 5) + (j >> 2)) * GBM;  // chunk 0..255, within-XCD reuse

    int tid  = threadIdx.x;
    int wave = tid >> 6;
    int lane = tid & 63;
    int wr   = wave >> 1;      // 0..1 : rows wr*64
    int wc   = wave & 1;       // 0..1 : cols wc*128
    int l16  = lane & 15;
    int lq   = lane >> 4;      // 0..3 : k-quarter (8 bf16)

    int sline = lane >> 3;
    int slog  = (lane & 7) ^ sline;
    int sh    = slog >> 2;
    int sq    = slog & 3;

    f32x4 acc[4][8];
#pragma unroll
    for (int m = 0; m < 4; ++m)
#pragma unroll
        for (int n = 0; n < 8; ++n)
            acc[m][n] = (f32x4){0.f, 0.f, 0.f, 0.f};

    auto stage = [&](int t, int b) {
        int k0 = t * GBK;
#pragma unroll
        for (int r = 0; r < 2; ++r) {
            int line = r * 32 + wave * 8 + sline;     // 0..63
            const unsigned short* gA =
                Xb + (size_t)(row0 + 2 * line + sh) * D_MODEL + k0 + sq * 8;
            __builtin_amdgcn_global_load_lds(
                (const __attribute__((address_space(1))) void*)gA,
                (__attribute__((address_space(3))) void*)&lds[b * ABUF_SHORTS + line * 64],
                16, 0, 0);
        }
#pragma unroll
        for (int r = 0; r < 4; ++r) {
            int line = r * 32 + wave * 8 + sline;     // 0..127
            const unsigned short* gB =
                Wp + (size_t)(col0 + 2 * line + sh) * D_MODEL + k0 + sq * 8;
            __builtin_amdgcn_global_load_lds(
                (const __attribute__((address_space(1))) void*)gB,
                (__attribute__((address_space(3))) void*)&lds[3 * ABUF_SHORTS + b * BBUF_SHORTS + line * 64],
                16, 0, 0);
        }
    };

    stage(0, 0);
    stage(1, 1);

    int cur = 0;   // t % 3
#pragma unroll 1
    for (int t = 0; t < GNT; ++t) {
        if (t + 1 < GNT) asm volatile("s_waitcnt vmcnt(6)" ::: "memory");
        else             asm volatile("s_waitcnt vmcnt(0)" ::: "memory");
        __builtin_amdgcn_s_barrier();

        if (t + 2 < GNT) {
            int bnext = cur >= 1 ? cur - 1 : cur + 2;   // (t+2)%3
            stage(t + 2, bnext);
        }

        const char* Ab = (const char*)&lds[cur * ABUF_SHORTS];
        const char* Bb = (const char*)&lds[3 * ABUF_SHORTS + cur * BBUF_SHORTS];

        bf16x8 bfr[8];
#pragma unroll
        for (int n = 0; n < 8; ++n) {
            int cc   = wc * 128 + n * 16 + l16;
            int line = cc >> 1;
            int o    = (((cc & 1) << 6) + (lq << 4)) ^ ((line & 7) << 4);
            bfr[n] = *reinterpret_cast<const bf16x8*>(Bb + line * 128 + o);
        }
        bf16x8 afr[4];
#pragma unroll
        for (int m = 0; m < 4; ++m) {
            int rr   = wr * 64 + m * 16 + l16;
            int line = rr >> 1;
            int o    = (((rr & 1) << 6) + (lq << 4)) ^ ((line & 7) << 4);
            afr[m] = *reinterpret_cast<const bf16x8*>(Ab + line * 128 + o);
        }

        __builtin_amdgcn_s_setprio(1);
#pragma unroll
        for (int m = 0; m < 4; ++m)
#pragma unroll
            for (int n = 0; n < 8; ++n)
                acc[m][n] = __builtin_amdgcn_mfma_f32_16x16x32_bf16(
                    afr[m], bfr[n], acc[m][n], 0, 0, 0);
        __builtin_amdgcn_s_setprio(0);

        cur = cur == 2 ? 0 : cur + 1;
    }

    // ---- epilogue: C/D col = lane&15, row = lq*4 + q; normal stores ----
    int crow = row0 + wr * 64;
    int ccol = col0 + wc * 128;
#pragma unroll
    for (int n = 0; n < 8; ++n) {
        int col = ccol + n * 16 + l16;
        float b = bias[col];
#pragma unroll
        for (int m = 0; m < 4; ++m) {
            int r = crow + m * 16 + lq * 4;
#pragma unroll
            for (int q = 0; q < 4; ++q)
                out[(size_t)(r + q) * D_MODEL + col] = acc[m][n][q] + b;
        }
    }
}

// ---------- launch ----------

extern "C" void kernel_launch(void* const* d_in, const int* in_sizes, int n_in,
                              void* d_out, int out_size, void* d_ws, size_t ws_size,
                              hipStream_t stream) {
    const float* x    = (const float*)d_in[0];
    const float* w    = (const float*)d_in[1];
    const float* bias = (const float*)d_in[2];
    float* out        = (float*)d_out;
    const int N       = in_sizes[0] / D_MODEL;   // 32768

    // ws: [16K, +2M) Wp | Xb (64M) | partial (8M) | partial2 (128K) | partial3 (64K)
    char* ws               = (char*)d_ws;
    unsigned short* Wp     = (unsigned short*)(ws + 16384);
    unsigned short* Xb     = (unsigned short*)(ws + 16384 + (size_t)D_MODEL * D_MODEL * 2);
    const int nPart        = N / CC_ROWS;   // 2048
    char*  after_xb        = ws + 16384 + (size_t)D_MODEL * D_MODEL * 2
                                        + (size_t)N * D_MODEL * 2;
    float* part            = (float*)after_xb;                                   // 2048 x 1024
    float* part2           = (float*)(after_xb + (size_t)nPart * D_MODEL * 4);   // 32 x 1024
    float* part3           = (float*)(after_xb + (size_t)nPart * D_MODEL * 4
                                               + (size_t)32 * D_MODEL * 4);      // 16 x 1024

    colmax_convert_w<<<nPart + 16, 256, 0, stream>>>(x, w, part, part3, Xb);
    reduce_partial<<<dim3(D_MODEL / 256, 32), 256, 0, stream>>>(part, part2);
    scale_buildw<<<D_MODEL, 256, 0, stream>>>(part2, part3, w, Wp);

    int nblk = (N / GBM) * (D_MODEL / GBN);   // 1024
    gemm_main<<<nblk, 256, 0, stream>>>(Xb, Wp, bias, out);
}